// Round 6
// baseline (1492.405 us; speedup 1.0000x reference)
//
#include <hip/hip_runtime.h>
#include <math.h>

typedef unsigned int u32;
typedef unsigned short u16;
typedef short s16x8 __attribute__((ext_vector_type(8)));
typedef float f32x4 __attribute__((ext_vector_type(4)));
typedef u16 u16x4 __attribute__((ext_vector_type(4)));
typedef u16 u16x8 __attribute__((ext_vector_type(8)));

#define B_  16
#define S_  2048
#define D_  1024
#define H_  256
#define SD_ 14
#define C_  6
#define G_  3
#define E_  18

static __device__ __forceinline__ u16 f2bf(float f) {
  u32 x = __builtin_bit_cast(u32, f);
  return (u16)((x + 0x7fffu + ((x >> 16) & 1u)) >> 16);
}

// ---------------- K3: convert features f32->bf16 + column-mean pooling ----------------
__global__ __launch_bounds__(256) void k_convpool(const float* __restrict__ F,
                                                  u16* __restrict__ Fbf,
                                                  float* __restrict__ fsum) {
  const int bb = blockIdx.x >> 5;
  const int sc = blockIdx.x & 31;
  const int t  = threadIdx.x;
  const size_t base = (size_t)(bb * S_ + sc * 64) * D_ + t * 4;
  float s0 = 0.f, s1 = 0.f, s2 = 0.f, s3 = 0.f;
  for (int i = 0; i < 64; ++i) {
    const f32x4 v = *(const f32x4*)(F + base + (size_t)i * D_);
    s0 += v[0]; s1 += v[1]; s2 += v[2]; s3 += v[3];
    u16x4 h;
    h[0] = f2bf(v[0]); h[1] = f2bf(v[1]); h[2] = f2bf(v[2]); h[3] = f2bf(v[3]);
    *(u16x4*)(Fbf + base + (size_t)i * D_) = h;
  }
  const int c = t * 4;
  atomicAdd(&fsum[bb * D_ + c + 0], s0);
  atomicAdd(&fsum[bb * D_ + c + 1], s1);
  atomicAdd(&fsum[bb * D_ + c + 2], s2);
  atomicAdd(&fsum[bb * D_ + c + 3], s3);
}

// ---------------- K3b: pooling only (lean path) ----------------
__global__ __launch_bounds__(256) void k_poolF(const float* __restrict__ F,
                                               float* __restrict__ fsum) {
  const int bb = blockIdx.x >> 5;
  const int sc = blockIdx.x & 31;
  const int t  = threadIdx.x;
  const size_t base = (size_t)(bb * S_ + sc * 64) * D_ + t * 4;
  float s0 = 0.f, s1 = 0.f, s2 = 0.f, s3 = 0.f;
  for (int i = 0; i < 64; ++i) {
    const f32x4 v = *(const f32x4*)(F + base + (size_t)i * D_);
    s0 += v[0]; s1 += v[1]; s2 += v[2]; s3 += v[3];
  }
  const int c = t * 4;
  atomicAdd(&fsum[bb * D_ + c + 0], s0);
  atomicAdd(&fsum[bb * D_ + c + 1], s1);
  atomicAdd(&fsum[bb * D_ + c + 2], s2);
  atomicAdd(&fsum[bb * D_ + c + 3], s3);
}

// ---------------- K1: x_raw column-mean pooling ----------------
__global__ __launch_bounds__(256) void k_xpool(const float* __restrict__ X,
                                               float* __restrict__ xsum) {
  const int b = blockIdx.x;
  const int t = threadIdx.x;
  float ls[SD_];
  #pragma unroll
  for (int c = 0; c < SD_; ++c) ls[c] = 0.f;
  for (int s = t; s < S_; s += 256) {
    const float* row = X + (size_t)(b * S_ + s) * SD_;
    #pragma unroll
    for (int c = 0; c < SD_; ++c) ls[c] += row[c];
  }
  #pragma unroll
  for (int c = 0; c < SD_; ++c) atomicAdd(&xsum[b * SD_ + c], ls[c]);
}

// ---------------- K2: routers + flat weights + expert loads + lb + bias term ----------------
__global__ __launch_bounds__(256) void k_router(const float* __restrict__ fsum,
                                                const float* __restrict__ xsum,
                                                const float* __restrict__ cond_w,
                                                const float* __restrict__ cond_b,
                                                const float* __restrict__ stage_w,
                                                const float* __restrict__ stage_b,
                                                const float* __restrict__ up_b,
                                                float* __restrict__ flatw,
                                                float* __restrict__ biasws,
                                                float* __restrict__ out_tail) {
  __shared__ float s_cl[B_][C_], s_sl[B_][G_];
  __shared__ float s_cw[B_][C_], s_sw[B_][G_];
  __shared__ float s_fw[B_][E_], s_ld[E_];
  const int t = threadIdx.x;
  if (t < B_ * C_) {
    const int b = t / C_, c = t % C_;
    float a = cond_b[c];
    for (int d = 0; d < D_; ++d) a += (fsum[b * D_ + d] * (1.f / S_)) * cond_w[d * C_ + c];
    s_cl[b][c] = a;
  }
  if (t < B_ * G_) {
    const int b = t / G_, g = t % G_;
    float a = stage_b[g];
    for (int sd = 0; sd < SD_; ++sd) a += (xsum[b * SD_ + sd] * (1.f / S_)) * stage_w[sd * G_ + g];
    s_sl[b][g] = a;
  }
  __syncthreads();
  if (t < B_) {
    float m = s_cl[t][0];
    for (int c = 1; c < C_; ++c) m = fmaxf(m, s_cl[t][c]);
    float den = 0.f, ex[C_];
    for (int c = 0; c < C_; ++c) { ex[c] = expf(s_cl[t][c] - m); den += ex[c]; }
    for (int c = 0; c < C_; ++c) s_cw[t][c] = ex[c] / den;
    float m2 = s_sl[t][0];
    for (int g = 1; g < G_; ++g) m2 = fmaxf(m2, s_sl[t][g]);
    float den2 = 0.f, ex2[G_];
    for (int g = 0; g < G_; ++g) { ex2[g] = expf(s_sl[t][g] - m2); den2 += ex2[g]; }
    for (int g = 0; g < G_; ++g) s_sw[t][g] = ex2[g] / den2;
    for (int c = 0; c < C_; ++c)
      for (int g = 0; g < G_; ++g) s_fw[t][c * G_ + g] = s_cw[t][c] * s_sw[t][g];
  }
  __syncthreads();
  if (t < B_ * C_) out_tail[t] = s_cw[t / C_][t % C_];
  if (t < B_ * G_) out_tail[B_ * C_ + t] = s_sw[t / G_][t % G_];
  for (int i = t; i < B_ * E_; i += 256) flatw[i] = s_fw[i / E_][i % E_];
  if (t < E_) {
    float a = 0.f;
    for (int b = 0; b < B_; ++b) a += s_fw[b][t];
    s_ld[t] = a / (float)B_;
    out_tail[B_ * C_ + B_ * G_ + t] = s_ld[t];
  }
  __syncthreads();
  if (t == 0) {
    float a = 0.f;
    for (int e = 0; e < E_; ++e) a += s_ld[e] * s_ld[e];
    out_tail[B_ * C_ + B_ * G_ + E_] = (float)E_ * a * 0.01f;
  }
  for (int i = t; i < B_ * D_; i += 256) {
    const int b = i >> 10, d = i & 1023;
    float a = 0.f;
    #pragma unroll
    for (int e = 0; e < E_; ++e) a += s_fw[b][e] * up_b[e * D_ + d];
    biasws[i] = a;
  }
}

// ---------------- K4: fragmentizer ----------------
// src: [E][K][N] f32 -> dst frag-linear bf16 [e][kb=K/32][cb=N/16][lane=64][8]:
//   dst = src[e][kb*32 + (lane>>4)*8 + j][cb*16 + (lane&15)]
__global__ __launch_bounds__(256) void k_frag(const float* __restrict__ src,
                                              u16* __restrict__ dst, int K, int N) {
  const int kgrp = K >> 7;
  const int ncb = N >> 4;
  const int bid = blockIdx.x;
  const int kbg = bid % kgrp;
  const int cb  = (bid / kgrp) % ncb;
  const int e   = bid / (kgrp * ncb);
  __shared__ float tile[128][17];
  const int t = threadIdx.x;
  #pragma unroll
  for (int it = 0; it < 8; ++it) {
    const int i = it * 256 + t;
    const int row = i >> 4, col = i & 15;
    tile[row][col] = src[((size_t)e * K + kbg * 128 + row) * N + cb * 16 + col];
  }
  __syncthreads();
  const int lane = t & 63, kbq = t >> 6;
  const int l15 = lane & 15, lhi = lane >> 4;
  const int kb = kbg * 4 + kbq;
  u16x8 h;
  #pragma unroll
  for (int j = 0; j < 8; ++j) h[j] = f2bf(tile[kbq * 32 + lhi * 8 + j][l15]);
  *(u16x8*)(dst + ((((size_t)e * (K >> 5) + kb) * ncb + cb) * 64 + lane) * 8) = h;
}

#define MFMA_BF16 __builtin_amdgcn_mfma_f32_16x16x32_bf16

// fast gelu (tanh form via exp2)
static __device__ __forceinline__ float gelu_f(float x) {
  float y2 = 2.302208f * x * (1.f + 0.044715f * x * x);
  y2 = fminf(fmaxf(y2, -30.f), 30.f);
  const float p = __builtin_exp2f(y2);
  return x * p / (p + 1.f);
}

// ---------------- K5: fused MoE main kernel (v6: BM=64, 16 waves) ----------------
// 64 rows x D=1024 per WG, 512 WGs, 1024 thr (16 waves = 4/SIMD -> 2x latency
// hiding vs v5) under a HARD 128-reg cap (512-reg file / 4 waves). acc=64.
// Down: wave w owns h-cols [w*16,+16) (cb=w), all 64 rows: hacc[4]=16 regs,
//   pb dbuf=8, unique B loads. Up: wave w owns out-cols [w*64,+64): acc[4][4],
//   ua[4]=16, ub dbuf[2][4]=32. Single Hb (32KiB) -> 2 barriers/expert.
// LDS = 128(F) + 32(Hb) = 160 KiB. Weight L3 traffic halves vs v5 (512 WGs),
// and 32 CUs/XCD stream the same ~1MB/expert -> L2-served.
template<int LEAN>
__global__ __launch_bounds__(1024, 4) void k_moe(const u16* __restrict__ Fbf,
                                                 const float* __restrict__ Ff32,
                                                 const u16* __restrict__ dwF,   // [e][32][16][64][8]
                                                 const u16* __restrict__ uwF,   // [e][8][64][64][8]
                                                 const float* __restrict__ down_b,
                                                 const float* __restrict__ flatw,
                                                 const float* __restrict__ biasws,
                                                 float* __restrict__ out) {
  __shared__ u16 Fb[64 * 1024];   // 128 KiB, row stride 2048B, XOR-swizzled 16B slots
  __shared__ u16 Hb[64 * 256];    // 32 KiB, row stride 512B, XOR-swizzled

  const int tile = blockIdx.x;
  const int r0 = tile * 64;
  const int b = r0 >> 11;
  const int t = threadIdx.x;
  const int w = t >> 6;          // 0..15
  const int l = t & 63;
  const int l15 = l & 15;
  const int lhi = l >> 4;
  const int sw7 = (l & 7) << 4;

  // ---- stage F tile (once, reused by all 18 experts) ----
  #pragma unroll
  for (int i = 0; i < 8; ++i) {
    const int slot = i * 1024 + t;  // 8192 16B slots
    const int row = slot >> 7;      // 0..63
    const int isl = slot & 127;
    char* dst = (char*)Fb + row * 2048 + ((isl * 16) ^ ((row & 7) << 4));
    if constexpr (!LEAN) {
      *(u16x8*)dst = *(const u16x8*)(Fbf + (size_t)(r0 + row) * D_ + isl * 8);
    } else {
      const float* src = Ff32 + (size_t)(r0 + row) * D_ + isl * 8;
      const f32x4 v0 = *(const f32x4*)src;
      const f32x4 v1 = *(const f32x4*)(src + 4);
      u16x8 h;
      h[0] = f2bf(v0[0]); h[1] = f2bf(v0[1]); h[2] = f2bf(v0[2]); h[3] = f2bf(v0[3]);
      h[4] = f2bf(v1[0]); h[5] = f2bf(v1[1]); h[6] = f2bf(v1[2]); h[7] = f2bf(v1[3]);
      *(u16x8*)dst = h;
    }
  }

  // preload expert-0 down-B (cb=w), kk=0,1  (frag = dwF[((e*32+kk)*16+cb)*512 + l*8])
  s16x8 pb[2];
  #pragma unroll
  for (int p = 0; p < 2; ++p)
    pb[p] = *(const s16x8*)(dwF + ((size_t)p * 16 + w) * 512 + l * 8);

  f32x4 acc[4][4];
  #pragma unroll
  for (int i = 0; i < 4; ++i)
    #pragma unroll
    for (int j = 0; j < 4; ++j)
      acc[i][j] = f32x4{0.f, 0.f, 0.f, 0.f};

  __syncthreads();

  const float* fwb = flatw + b * E_;

  #pragma unroll 1
  for (int e = 0; e < E_; ++e) {
    // ---- DOWN: h[64 x 16cols/wave] = F(64x1024) @ dw[e] ----
    f32x4 hacc[4];
    #pragma unroll
    for (int fr = 0; fr < 4; ++fr) hacc[fr] = f32x4{0.f, 0.f, 0.f, 0.f};
    #pragma unroll
    for (int kk = 0; kk < 32; ++kk) {
      s16x8 a[4];
      #pragma unroll
      for (int fr = 0; fr < 4; ++fr)
        a[fr] = *(const s16x8*)((const char*)Fb + (fr * 16 + l15) * 2048 +
                                ((kk * 64 + lhi * 16) ^ sw7));
      const s16x8 bb = pb[kk & 1];
      if (kk < 30)
        pb[kk & 1] = *(const s16x8*)(dwF + ((size_t)(e * 32 + kk + 2) * 16 + w) * 512 + l * 8);
      #pragma unroll
      for (int fr = 0; fr < 4; ++fr)
        hacc[fr] = MFMA_BF16(a[fr], bb, hacc[fr], 0, 0, 0);
    }

    // issue up-B(ks=0) loads (independent of Hb)
    const size_t ubase = ((size_t)e * 8 * 64 + (size_t)w * 4) * 512 + l * 8;
    s16x8 ub[2][4];
    #pragma unroll
    for (int fc = 0; fc < 4; ++fc)
      ub[0][fc] = *(const s16x8*)(uwF + ubase + (size_t)fc * 512);

    __syncthreads();  // BARRIER1: all waves done reading Hb for expert e-1

    // ---- gelu + routing-scale -> Hb ----
    const float wbe = fwb[e];
    {
      const int hc = w * 16 + l15;
      const float dbv = down_b[e * H_ + hc];
      #pragma unroll
      for (int fr = 0; fr < 4; ++fr) {
        #pragma unroll
        for (int i = 0; i < 4; ++i) {
          const int row = fr * 16 + lhi * 4 + i;
          const float x = hacc[fr][i] + dbv;
          *(u16*)((char*)Hb + row * 512 + ((hc * 2) ^ ((row & 7) << 4))) = f2bf(gelu_f(x) * wbe);
        }
      }
    }

    // preload next-expert down-B kk=0,1
    if (e + 1 < E_) {
      #pragma unroll
      for (int p = 0; p < 2; ++p)
        pb[p] = *(const s16x8*)(dwF + ((size_t)((e + 1) * 32 + p) * 16 + w) * 512 + l * 8);
    }

    __syncthreads();  // BARRIER2: Hb published

    // ---- UP: acc[64 x 64cols/wave] += Hb(64x256) @ uw[e] ----
    #pragma unroll
    for (int ks = 0; ks < 8; ++ks) {
      s16x8 ua[4];
      #pragma unroll
      for (int fr = 0; fr < 4; ++fr)
        ua[fr] = *(const s16x8*)((const char*)Hb + (fr * 16 + l15) * 512 +
                                 ((ks * 64 + lhi * 16) ^ sw7));
      if (ks < 7) {
        #pragma unroll
        for (int fc = 0; fc < 4; ++fc)
          ub[(ks + 1) & 1][fc] =
              *(const s16x8*)(uwF + ubase + ((size_t)(ks + 1) * 64 + fc) * 512);
      }
      #pragma unroll
      for (int fc = 0; fc < 4; ++fc) {
        #pragma unroll
        for (int fr = 0; fr < 4; ++fr)
          acc[fr][fc] = MFMA_BF16(ua[fr], ub[ks & 1][fc], acc[fr][fc], 0, 0, 0);
      }
    }
  }

  // ---- epilogue: residual + bias + store ----
  const float* bias = biasws + b * D_;
  #pragma unroll
  for (int fc = 0; fc < 4; ++fc) {
    const int col = w * 64 + fc * 16 + l15;
    const float bv = bias[col];
    #pragma unroll
    for (int fr = 0; fr < 4; ++fr) {
      #pragma unroll
      for (int i = 0; i < 4; ++i) {
        const int row = fr * 16 + lhi * 4 + i;
        const size_t idx = (size_t)(r0 + row) * D_ + col;
        out[idx] = acc[fr][fc][i] + Ff32[idx] + bv;
      }
    }
  }
}

extern "C" void kernel_launch(void* const* d_in, const int* in_sizes, int n_in,
                              void* d_out, int out_size, void* d_ws, size_t ws_size,
                              hipStream_t stream) {
  const float* F  = (const float*)d_in[0];
  const float* X  = (const float*)d_in[1];
  const float* dw = (const float*)d_in[2];
  const float* db = (const float*)d_in[3];
  const float* uw = (const float*)d_in[4];
  const float* ub = (const float*)d_in[5];
  const float* cw = (const float*)d_in[6];
  const float* cb = (const float*)d_in[7];
  const float* sw = (const float*)d_in[8];
  const float* sb = (const float*)d_in[9];
  float* out = (float*)d_out;

  char* ws = (char*)d_ws;
  float* fsum  = (float*)ws;                 // B*D
  float* xsum  = fsum + B_ * D_;             // B*SD
  float* flatw = xsum + B_ * SD_;            // B*E
  float* biasws = flatw + B_ * E_;           // B*D
  size_t off = (size_t)(B_ * D_ + B_ * SD_ + B_ * E_ + B_ * D_) * 4;
  off = (off + 255) & ~(size_t)255;
  u16* dwF = (u16*)(ws + off); off += (size_t)E_ * H_ * D_ * 2;
  u16* uwF = (u16*)(ws + off); off += (size_t)E_ * D_ * H_ * 2;
  const size_t need_lean = off;
  u16* Fbf = (u16*)(ws + off); off += (size_t)B_ * S_ * D_ * 2;
  const size_t need_full = off;

  if (ws_size < need_lean) return;
  const bool lean = ws_size < need_full;

  hipMemsetAsync(d_ws, 0, (size_t)(B_ * D_ + B_ * SD_) * sizeof(float), stream);
  k_frag<<<E_ * (H_ / 16) * (D_ / 128), 256, 0, stream>>>(dw, dwF, D_, H_);
  k_frag<<<E_ * (D_ / 16) * (H_ / 128), 256, 0, stream>>>(uw, uwF, H_, D_);
  if (!lean) {
    k_convpool<<<512, 256, 0, stream>>>(F, Fbf, fsum);
  } else {
    k_poolF<<<512, 256, 0, stream>>>(F, fsum);
  }
  k_xpool<<<B_, 256, 0, stream>>>(X, xsum);
  k_router<<<1, 256, 0, stream>>>(fsum, xsum, cw, cb, sw, sb, ub, flatw, biasws,
                                  out + (size_t)B_ * S_ * D_);
  if (!lean) {
    k_moe<0><<<512, 1024, 0, stream>>>(Fbf, F, dwF, uwF, db, flatw, biasws, out);
  } else {
    k_moe<1><<<512, 1024, 0, stream>>>(nullptr, F, dwF, uwF, db, flatw, biasws, out);
  }
}